// Round 17
// baseline (65.318 us; speedup 1.0000x reference)
//
#include <hip/hip_runtime.h>
#include <math.h>

// ConcentrationPredictor: 32 RK4 steps of dc/dt = flux(c), per-cell MLP D_eff.
// R17: wave-autonomous 1-wave blocks (TPB=64), interleaved 2 cells/thread
// (validated R6/R16 shfl exchange), ZERO barriers and ZERO LDS: the 45KB
// asinh-space cubic-Hermite table is gathered straight from L1/L2 via one
// float4 load per evaluation (tab[i], tab[i+1] are contiguous). Kills R16's
// per-block table staging (45KB x 1024 instances), all bank conflicts, and
// the barrier convoy. Schedule S=11,11,10 -> 3 rk4 dispatches; halo 44,
// inner 40/wave, 1639 blocks = 6.4/CU = 1.6 waves/SIMD.

constexpr int TPB     = 64;                // one wave per block
constexpr int W_HALO  = 44;                // covers 4*11 contamination
constexpr int W_INNER = 40;                // 128 - 2*44

constexpr int   NTAB   = 5633;             // nodes: u in [-22,22], h = 1/128
constexpr float VSLOPE = 88.72283911167299f;  // ln2 * 128
constexpr float VOFF   = 2816.0f;             // -U_MIN * 128
constexpr float HSTEP  = 0.0078125f;          // h = 1/128

// float-layout of d_ws:
//   [0 .. 2*NTAB)        float2 table (v, dv/du) per node
//   [2*NTAB]             scale = 10^p_exp
//   [2*NTAB+1 .. +32]    A[s] = (t[s+1]-t[s]) * 0.3125f
constexpr int F_SCALE = 2 * NTAB;          // 11266
constexpr int F_A0    = 2 * NTAB + 1;      // 11267

// ---------- prep: build ret table (value + d/du) with accurate math ----------
__global__ __launch_bounds__(256)
void build_tab_kernel(const float* __restrict__ W1, const float* __restrict__ b1,
                      const float* __restrict__ W2, const float* __restrict__ b2,
                      const float* __restrict__ W3, const float* __restrict__ b3,
                      const float* __restrict__ W4, const float* __restrict__ b4,
                      const float* __restrict__ p_exp, const float* __restrict__ t,
                      int nsteps, float* __restrict__ wsf)
{
    const int i = blockIdx.x * blockDim.x + threadIdx.x;
    if (i > NTAB) {
        const int s = i - NTAB - 1;          // aux: A[s]
        if (s < nsteps && s < 32)
            wsf[F_A0 + s] = (t[s + 1] - t[s]) * 0.3125f;
        return;
    }
    if (i == NTAB) {                          // aux: scale
        wsf[F_SCALE] = powf(10.0f, p_exp[0]);
        return;
    }
    const float u  = -22.0f + (float)i * HSTEP;
    const float y  = sinhf(u);     // MLP input at this node
    const float yd = coshf(u);     // dy/du

    float h[15], hd[15], g[15], gd[15];
#pragma unroll
    for (int j = 0; j < 15; ++j) {
        float a  = fmaf(y, W1[j], b1[j]);
        float ad = yd * W1[j];
        float th = tanhf(a);
        h[j]  = th;
        hd[j] = (1.0f - th * th) * ad;
    }
#pragma unroll
    for (int j = 0; j < 15; ++j) {
        float a = b2[j], ad = 0.0f;
#pragma unroll
        for (int k = 0; k < 15; ++k) {
            a  = fmaf(h[k],  W2[k * 15 + j], a);
            ad = fmaf(hd[k], W2[k * 15 + j], ad);
        }
        float th = tanhf(a);
        g[j]  = th;
        gd[j] = (1.0f - th * th) * ad;
    }
#pragma unroll
    for (int j = 0; j < 15; ++j) {
        float a = b3[j], ad = 0.0f;
#pragma unroll
        for (int k = 0; k < 15; ++k) {
            a  = fmaf(g[k],  W3[k * 15 + j], a);
            ad = fmaf(gd[k], W3[k * 15 + j], ad);
        }
        float th = tanhf(a);
        h[j]  = th;
        hd[j] = (1.0f - th * th) * ad;
    }
    float o = b4[0], od = 0.0f;
#pragma unroll
    for (int k = 0; k < 15; ++k) {
        o  = fmaf(h[k],  W4[k], o);
        od = fmaf(hd[k], W4[k], od);
    }
    const float s = 1.0f / (1.0f + expf(-o));     // sigmoid
    wsf[2 * i]     = s;                           // value
    wsf[2 * i + 1] = s * (1.0f - s) * od;         // d/du
}

// ---------- table evaluation: ret(c*scale), global gather + cubic Hermite ----
__device__ __forceinline__ float ret_tab(float c, float scale,
                                         const float* __restrict__ wsf)
{
    const float y  = c * scale;
    const float ay = fabsf(y);
    // u = asinh(y); v = (u + 22)*128 folded into one fma off v_log_f32 (log2)
    const float w  = ay + __builtin_amdgcn_sqrtf(fmaf(ay, ay, 1.0f));
    const float m  = copysignf(VSLOPE, y);
    float v = fmaf(__builtin_amdgcn_logf(w), m, VOFF);
    v = fminf(fmaxf(v, 0.0f), (float)(NTAB - 2) + 0.999f);  // clamp to table
    const int   i   = (int)v;
    const float tau = v - (float)i;

    // both Hermite nodes in one 16B load (dword-aligned is sufficient)
    const float4 AB = *(const float4*)(wsf + 2 * i);
    const float t2 = tau * tau;
    const float t3 = t2 * tau;
    return AB.x * (2.0f * t3 - 3.0f * t2 + 1.0f)
         + AB.z * (3.0f * t2 - 2.0f * t3)
         + HSTEP * (AB.y * (t3 - 2.0f * t2 + tau) + AB.w * (t3 - t2));
}

__global__ __launch_bounds__(TPB)
void rk4_kernel(const float* __restrict__ src,   // state at step s0 [N]
                float* __restrict__ out,         // [T, N]
                const float* __restrict__ wsf,   // table+aux in d_ws
                int N, int s0, int nsub)
{
    const int lane = threadIdx.x;    // TPB == 64, one wave
    const int base = blockIdx.x * W_INNER - W_HALO;
    const int g0   = base + 2 * lane;    // even cell
    const int g1   = g0 + 1;             // odd cell

    float cx = src[min(max(g0, 0), N - 1)];
    float cy = src[min(max(g1, 0), N - 1)];

    // valid window cells [W_HALO, W_HALO + W_INNER) = [44, 84) -> lanes [22, 42)
    const bool valid = (lane >= W_HALO / 2) && (lane < (W_HALO + W_INNER) / 2);

    if (s0 == 0 && valid) {
        if ((unsigned)g0 < (unsigned)N) out[g0] = cx;
        if ((unsigned)g1 < (unsigned)N) out[g1] = cy;
    }

    const float scale = wsf[F_SCALE];

    // one flux stage, k~ = flux/D0 (D0 folded into A).
    // Interleaved neighbors (validated R6/R16): even cell 2L: cl=shfl_up(cy),
    // cr=own cy; odd cell 2L+1: cl=own cx, cr=shfl_down(cx).
    auto stage = [&](float ccx, float ccy, float& fx, float& fy) {
        float up = __shfl_up(ccy, 1, 64);     // cell 2L-1
        float dn = __shfl_down(ccx, 1, 64);   // cell 2L+2
        float rx = ret_tab(ccx, scale, wsf);
        float ry = ret_tab(ccy, scale, wsf);
        if (g0 == 0)                    // N even -> only even comp can be cell 0
            fx = rx * ((1.0f - ccx) + (ccy - ccx));
        else
            fx = rx * (up + ccy - 2.0f * ccx);
        if (g1 == N - 1)                // N-1 odd -> only odd comp
            fy = ry * ((ccx - ccy) + (0.0125f * (ccx - ccy) - ccy));
        else
            fy = ry * (ccx + dn - 2.0f * ccy);
    };

#pragma unroll 1
    for (int s = 0; s < nsub; ++s) {
        const float A = wsf[F_A0 + s0 + s];   // uniform (scalarized) load

        float k1x, k1y, k2x, k2y, k3x, k3y, k4x, k4y;
        stage(cx, cy, k1x, k1y);
        float c2x = fmaf(0.5f * A, k1x, cx), c2y = fmaf(0.5f * A, k1y, cy);
        stage(c2x, c2y, k2x, k2y);
        float c3x = fmaf(0.5f * A, k2x, cx), c3y = fmaf(0.5f * A, k2y, cy);
        stage(c3x, c3y, k3x, k3y);
        float c4x = fmaf(A, k3x, cx), c4y = fmaf(A, k3y, cy);
        stage(c4x, c4y, k4x, k4y);

        cx = fmaf(A * (1.0f / 6.0f), k1x + 2.0f * (k2x + k3x) + k4x, cx);
        cy = fmaf(A * (1.0f / 6.0f), k1y + 2.0f * (k2y + k3y) + k4y, cy);

        if (valid) {
            float* row = out + (size_t)(s0 + s + 1) * N;
            if ((unsigned)g0 < (unsigned)N) row[g0] = cx;
            if ((unsigned)g1 < (unsigned)N) row[g1] = cy;
        }
    }
}

extern "C" void kernel_launch(void* const* d_in, const int* in_sizes, int n_in,
                              void* d_out, int out_size, void* d_ws, size_t ws_size,
                              hipStream_t stream)
{
    const float* c0    = (const float*)d_in[0];
    const float* t     = (const float*)d_in[1];
    const float* W1    = (const float*)d_in[2];
    const float* b1    = (const float*)d_in[3];
    const float* W2    = (const float*)d_in[4];
    const float* b2    = (const float*)d_in[5];
    const float* W3    = (const float*)d_in[6];
    const float* b3    = (const float*)d_in[7];
    const float* W4    = (const float*)d_in[8];
    const float* b4    = (const float*)d_in[9];
    const float* p_exp = (const float*)d_in[10];

    float* out = (float*)d_out;
    float* wsf = (float*)d_ws;   // table + aux

    const int N      = in_sizes[0];       // 65536
    const int nsteps = in_sizes[1] - 1;   // 32

    // build ret table + aux (scale, A[s])
    const int tgrid = (NTAB + 1 + 32 + 255) / 256;
    hipLaunchKernelGGL(build_tab_kernel, dim3(tgrid), dim3(256), 0, stream,
                       W1, b1, W2, b2, W3, b3, W4, b4, p_exp, t, nsteps, wsf);

    const int grid = (N + W_INNER - 1) / W_INNER;   // 1639 one-wave blocks

    // schedule: 11, 11, 10 steps (halo 44 covers 4*11)
    for (int s0 = 0; s0 < nsteps; ) {
        const int nsub = min(11, nsteps - s0);
        const float* src = (s0 == 0) ? c0 : out + (size_t)s0 * N;
        hipLaunchKernelGGL(rk4_kernel, dim3(grid), dim3(TPB), 0, stream,
                           src, out, wsf, N, s0, nsub);
        s0 += nsub;
    }
}

// Round 18
// 57.881 us; speedup vs baseline: 1.1285x; 1.1285x over previous
//
#include <hip/hip_runtime.h>
#include <math.h>

// ConcentrationPredictor: 32 RK4 steps of dc/dt = flux(c), per-cell MLP D_eff.
// R18 = R14 (single rk4 dispatch, TPB=512, inner 256, grid 256, LDS table,
// per-stage barriers, hoisted gathers, LDS A[s], sentinel halo buffers) +
// WAVE-PARITY GATHER SPLIT: even waves gather the cubic-Hermite table from
// LDS, odd waves gather the identical table from d_ws (L1/L2-resident) via
// global float4 loads. Halves LDS gather volume + bank conflicts; puts the
// otherwise-idle vector-memory pipe to work. Wave-uniform select -> no
// divergence. Same table bits, same arithmetic as R14.
// build_tab: libm tanhf/expf -> __expf-based fast forms (R2-validated class).

constexpr int TPB     = 512;
constexpr int S_FUSE  = 32;
constexpr int HALO    = 4 * S_FUSE;        // 128
constexpr int B_INNER = TPB - 2 * HALO;    // 256

constexpr int   NTAB   = 5633;             // nodes: u in [-22,22], h = 1/128
constexpr float VSLOPE = 88.72283911167299f;  // ln2 * 128
constexpr float VOFF   = 2816.0f;             // -U_MIN * 128
constexpr float HSTEP  = 0.0078125f;          // h = 1/128

// float-layout of d_ws / LDS:
//   [0 .. 2*NTAB)        float2 table (v, dv/du) per node
//   [2*NTAB]             scale = 10^p_exp
//   [2*NTAB+1 .. +32]    A[s] = (t[s+1]-t[s]) * 0.3125f
constexpr int F_SCALE = 2 * NTAB;          // 11266
constexpr int F_A0    = 2 * NTAB + 1;      // 11267
constexpr int F_TOT   = 2 * NTAB + 1 + 32; // 11299
constexpr int F4_TOT  = (F_TOT + 3) / 4;   // 2825 float4s staged

__device__ __forceinline__ float fast_tanh(float x) {
    float e = __expf(2.0f * x);
    return 1.0f - 2.0f * __builtin_amdgcn_rcpf(1.0f + e);
}

// ---------- prep: build ret table (value + d/du) ----------
__global__ __launch_bounds__(256)
void build_tab_kernel(const float* __restrict__ W1, const float* __restrict__ b1,
                      const float* __restrict__ W2, const float* __restrict__ b2,
                      const float* __restrict__ W3, const float* __restrict__ b3,
                      const float* __restrict__ W4, const float* __restrict__ b4,
                      const float* __restrict__ p_exp, const float* __restrict__ t,
                      int nsteps, float* __restrict__ wsf)
{
    const int i = blockIdx.x * blockDim.x + threadIdx.x;
    if (i > NTAB) {
        const int s = i - NTAB - 1;          // aux: A[s]
        if (s < nsteps && s < 32)
            wsf[F_A0 + s] = (t[s + 1] - t[s]) * 0.3125f;
        return;
    }
    if (i == NTAB) {                          // aux: scale
        wsf[F_SCALE] = powf(10.0f, p_exp[0]);
        return;
    }
    const float u  = -22.0f + (float)i * HSTEP;
    const float y  = sinhf(u);     // MLP input at this node
    const float yd = coshf(u);     // dy/du

    float h[15], hd[15], g[15], gd[15];
#pragma unroll
    for (int j = 0; j < 15; ++j) {
        float a  = fmaf(y, W1[j], b1[j]);
        float ad = yd * W1[j];
        float th = fast_tanh(a);
        h[j]  = th;
        hd[j] = (1.0f - th * th) * ad;
    }
#pragma unroll
    for (int j = 0; j < 15; ++j) {
        float a = b2[j], ad = 0.0f;
#pragma unroll
        for (int k = 0; k < 15; ++k) {
            a  = fmaf(h[k],  W2[k * 15 + j], a);
            ad = fmaf(hd[k], W2[k * 15 + j], ad);
        }
        float th = fast_tanh(a);
        g[j]  = th;
        gd[j] = (1.0f - th * th) * ad;
    }
#pragma unroll
    for (int j = 0; j < 15; ++j) {
        float a = b3[j], ad = 0.0f;
#pragma unroll
        for (int k = 0; k < 15; ++k) {
            a  = fmaf(g[k],  W3[k * 15 + j], a);
            ad = fmaf(gd[k], W3[k * 15 + j], ad);
        }
        float th = fast_tanh(a);
        h[j]  = th;
        hd[j] = (1.0f - th * th) * ad;
    }
    float o = b4[0], od = 0.0f;
#pragma unroll
    for (int k = 0; k < 15; ++k) {
        o  = fmaf(h[k],  W4[k], o);
        od = fmaf(hd[k], W4[k], od);
    }
    const float s = __builtin_amdgcn_rcpf(1.0f + __expf(-o));   // sigmoid
    wsf[2 * i]     = s;                           // value
    wsf[2 * i + 1] = s * (1.0f - s) * od;         // d/du
}

// ---------- table evaluation: ret(c*scale) via asinh + cubic Hermite --------
// use_lds is wave-uniform: even waves read the LDS copy, odd waves the global
// copy (L1/L2-resident) -> LDS gather traffic and bank conflicts halve.
__device__ __forceinline__ float ret_tab(float c, float scale,
                                         const float2* __restrict__ lds_tab,
                                         const float* __restrict__ gtab,
                                         bool use_lds)
{
    const float y  = c * scale;
    const float ay = fabsf(y);
    // u = asinh(y); v = (u + 22)*128 folded into one fma off v_log_f32 (log2)
    const float w  = ay + __builtin_amdgcn_sqrtf(fmaf(ay, ay, 1.0f));
    const float m  = copysignf(VSLOPE, y);
    float v = fmaf(__builtin_amdgcn_logf(w), m, VOFF);
    v = fminf(fmaxf(v, 0.0f), (float)(NTAB - 2) + 0.999f);  // clamp to table
    const int   i   = (int)v;
    const float tau = v - (float)i;

    float ax, ay2, bx, by;
    if (use_lds) {
        const float2 A = lds_tab[i];
        const float2 B = lds_tab[i + 1];
        ax = A.x; ay2 = A.y; bx = B.x; by = B.y;
    } else {
        const float4 AB = *(const float4*)(gtab + 2 * i);
        ax = AB.x; ay2 = AB.y; bx = AB.z; by = AB.w;
    }
    const float t2 = tau * tau;
    const float t3 = t2 * tau;
    return ax * (2.0f * t3 - 3.0f * t2 + 1.0f)
         + bx * (3.0f * t2 - 2.0f * t3)
         + HSTEP * (ay2 * (t3 - 2.0f * t2 + tau) + by * (t3 - t2));
}

// flux/D0 (D0 folded into the A coefficient)
__device__ __forceinline__ float flux_cell(float ret, float c, float cl, float cr,
                                           int g, int N)
{
    if (g == 0)
        return ret * ((1.0f - c) + (cr - c));
    if (g == N - 1) {
        float rbc = 0.0125f * (cl - c);   // D0*DX*(c[N-2]-c[N-1])
        return ret * ((cl - c) + (rbc - c));
    }
    return ret * (cl + cr - 2.0f * c);
}

__global__ __launch_bounds__(TPB)
void rk4_steps_kernel(const float* __restrict__ src,   // state at step s0 [N]
                      float* __restrict__ out,         // [T, N]
                      const float* __restrict__ wsf,   // table+aux in d_ws
                      int N, int s0, int nsub)
{
    __shared__ float tlds[F4_TOT * 4];   // table + aux (float4-staged)
    __shared__ float la[TPB + 2];        // sentinel slots [0] and [TPB+1]
    __shared__ float lb[TPB + 2];

    const int tid = threadIdx.x;

    // stage table+aux, float4-vectorized
    {
        const float4* __restrict__ s4 = (const float4*)wsf;
        float4* d4 = (float4*)tlds;
        for (int i = tid; i < F4_TOT; i += TPB) d4[i] = s4[i];
    }

    const int g  = blockIdx.x * B_INNER - HALO + tid;  // my global cell (may be OOB)
    const int gi = min(max(g, 0), N - 1);              // clamped load index

    float c = src[gi];

    const bool valid   = (tid >= HALO) && (tid < HALO + B_INNER) && (g < N);
    const bool use_lds = ((tid >> 6) & 1) == 0;        // wave-uniform parity

    // single launch also writes row 0 (replaces the D2D memcpy)
    if (s0 == 0 && valid) out[g] = c;

    __syncthreads();                  // table staged
    const float2* __restrict__ tab = (const float2*)tlds;
    const float scale = tlds[F_SCALE];

    for (int s = 0; s < nsub; ++s) {
        const float A = tlds[F_A0 + s];   // uniform broadcast, dt*D0

        // stage 1: gather hoisted above write+barrier (latency folds into
        // the barrier's wait)
        float ret1 = ret_tab(c, scale, tab, wsf, use_lds);
        la[tid + 1] = c;
        __syncthreads();
        float cl = la[tid], cr = la[tid + 2];
        float k1 = flux_cell(ret1, c, cl, cr, g, N);
        float c2 = fmaf(0.5f * A, k1, c);

        // stage 2
        float ret2 = ret_tab(c2, scale, tab, wsf, use_lds);
        lb[tid + 1] = c2;
        __syncthreads();
        cl = lb[tid]; cr = lb[tid + 2];
        float k2 = flux_cell(ret2, c2, cl, cr, g, N);
        float c3 = fmaf(0.5f * A, k2, c);

        // stage 3
        float ret3 = ret_tab(c3, scale, tab, wsf, use_lds);
        la[tid + 1] = c3;
        __syncthreads();
        cl = la[tid]; cr = la[tid + 2];
        float k3 = flux_cell(ret3, c3, cl, cr, g, N);
        float c4 = fmaf(A, k3, c);

        // stage 4
        float ret4 = ret_tab(c4, scale, tab, wsf, use_lds);
        lb[tid + 1] = c4;
        __syncthreads();
        cl = lb[tid]; cr = lb[tid + 2];
        float k4 = flux_cell(ret4, c4, cl, cr, g, N);

        c = fmaf(A * (1.0f / 6.0f), k1 + 2.0f * (k2 + k3) + k4, c);

        // write valid inner window of this step's new state
        if (valid)
            out[(size_t)(s0 + s + 1) * N + g] = c;
    }
}

extern "C" void kernel_launch(void* const* d_in, const int* in_sizes, int n_in,
                              void* d_out, int out_size, void* d_ws, size_t ws_size,
                              hipStream_t stream)
{
    const float* c0    = (const float*)d_in[0];
    const float* t     = (const float*)d_in[1];
    const float* W1    = (const float*)d_in[2];
    const float* b1    = (const float*)d_in[3];
    const float* W2    = (const float*)d_in[4];
    const float* b2    = (const float*)d_in[5];
    const float* W3    = (const float*)d_in[6];
    const float* b3    = (const float*)d_in[7];
    const float* W4    = (const float*)d_in[8];
    const float* b4    = (const float*)d_in[9];
    const float* p_exp = (const float*)d_in[10];

    float* out = (float*)d_out;
    float* wsf = (float*)d_ws;   // F_TOT floats = 45196 B

    const int N      = in_sizes[0];       // 65536
    const int nsteps = in_sizes[1] - 1;   // 32

    // build ret table + aux (scale, A[s])
    const int tgrid = (NTAB + 1 + 32 + 255) / 256;
    hipLaunchKernelGGL(build_tab_kernel, dim3(tgrid), dim3(256), 0, stream,
                       W1, b1, W2, b2, W3, b3, W4, b4, p_exp, t, nsteps, wsf);

    const int grid = (N + B_INNER - 1) / B_INNER;  // 256 -> 1 block/CU

    for (int s0 = 0; s0 < nsteps; s0 += S_FUSE) {   // single iteration for T=33
        const int nsub = min(S_FUSE, nsteps - s0);
        const float* src = (s0 == 0) ? c0 : out + (size_t)s0 * N;
        hipLaunchKernelGGL(rk4_steps_kernel, dim3(grid), dim3(TPB), 0, stream,
                           src, out, wsf, N, s0, nsub);
    }
}

// Round 19
// 50.272 us; speedup vs baseline: 1.2993x; 1.1514x over previous
//
#include <hip/hip_runtime.h>
#include <math.h>

// ConcentrationPredictor: 32 RK4 steps of dc/dt = flux(c), per-cell MLP D_eff.
// R19 = R14's measured-best rk4 structure (single dispatch, TPB=512, inner
// 256, grid 256 = 1 block/CU, LDS cubic-Hermite table in asinh space,
// per-stage barriers, hoisted gathers, LDS A[s], sentinel halo buffers)
// + R18's validated fast-math build_tab (__expf-based tanh/sigmoid, ~3us
// faster, absmax improved to 131072). R18's wave-parity gather split is
// REVERTED: profiling showed it cost +8us on the rk4 dispatch (global gather
// latency on the barrier-locked critical path > saved LDS conflicts).

constexpr int TPB     = 512;
constexpr int S_FUSE  = 32;
constexpr int HALO    = 4 * S_FUSE;        // 128
constexpr int B_INNER = TPB - 2 * HALO;    // 256

constexpr int   NTAB   = 5633;             // nodes: u in [-22,22], h = 1/128
constexpr float VSLOPE = 88.72283911167299f;  // ln2 * 128
constexpr float VOFF   = 2816.0f;             // -U_MIN * 128
constexpr float HSTEP  = 0.0078125f;          // h = 1/128

// float-layout of d_ws / LDS:
//   [0 .. 2*NTAB)        float2 table (v, dv/du) per node
//   [2*NTAB]             scale = 10^p_exp
//   [2*NTAB+1 .. +32]    A[s] = (t[s+1]-t[s]) * 0.3125f
constexpr int F_SCALE = 2 * NTAB;          // 11266
constexpr int F_A0    = 2 * NTAB + 1;      // 11267
constexpr int F_TOT   = 2 * NTAB + 1 + 32; // 11299
constexpr int F4_TOT  = (F_TOT + 3) / 4;   // 2825 float4s staged

__device__ __forceinline__ float fast_tanh(float x) {
    float e = __expf(2.0f * x);
    return 1.0f - 2.0f * __builtin_amdgcn_rcpf(1.0f + e);
}

// ---------- prep: build ret table (value + d/du) ----------
__global__ __launch_bounds__(256)
void build_tab_kernel(const float* __restrict__ W1, const float* __restrict__ b1,
                      const float* __restrict__ W2, const float* __restrict__ b2,
                      const float* __restrict__ W3, const float* __restrict__ b3,
                      const float* __restrict__ W4, const float* __restrict__ b4,
                      const float* __restrict__ p_exp, const float* __restrict__ t,
                      int nsteps, float* __restrict__ wsf)
{
    const int i = blockIdx.x * blockDim.x + threadIdx.x;
    if (i > NTAB) {
        const int s = i - NTAB - 1;          // aux: A[s]
        if (s < nsteps && s < 32)
            wsf[F_A0 + s] = (t[s + 1] - t[s]) * 0.3125f;
        return;
    }
    if (i == NTAB) {                          // aux: scale
        wsf[F_SCALE] = powf(10.0f, p_exp[0]);
        return;
    }
    const float u  = -22.0f + (float)i * HSTEP;
    const float y  = sinhf(u);     // MLP input at this node
    const float yd = coshf(u);     // dy/du

    float h[15], hd[15], g[15], gd[15];
#pragma unroll
    for (int j = 0; j < 15; ++j) {
        float a  = fmaf(y, W1[j], b1[j]);
        float ad = yd * W1[j];
        float th = fast_tanh(a);
        h[j]  = th;
        hd[j] = (1.0f - th * th) * ad;
    }
#pragma unroll
    for (int j = 0; j < 15; ++j) {
        float a = b2[j], ad = 0.0f;
#pragma unroll
        for (int k = 0; k < 15; ++k) {
            a  = fmaf(h[k],  W2[k * 15 + j], a);
            ad = fmaf(hd[k], W2[k * 15 + j], ad);
        }
        float th = fast_tanh(a);
        g[j]  = th;
        gd[j] = (1.0f - th * th) * ad;
    }
#pragma unroll
    for (int j = 0; j < 15; ++j) {
        float a = b3[j], ad = 0.0f;
#pragma unroll
        for (int k = 0; k < 15; ++k) {
            a  = fmaf(g[k],  W3[k * 15 + j], a);
            ad = fmaf(gd[k], W3[k * 15 + j], ad);
        }
        float th = fast_tanh(a);
        h[j]  = th;
        hd[j] = (1.0f - th * th) * ad;
    }
    float o = b4[0], od = 0.0f;
#pragma unroll
    for (int k = 0; k < 15; ++k) {
        o  = fmaf(h[k],  W4[k], o);
        od = fmaf(hd[k], W4[k], od);
    }
    const float s = __builtin_amdgcn_rcpf(1.0f + __expf(-o));   // sigmoid
    wsf[2 * i]     = s;                           // value
    wsf[2 * i + 1] = s * (1.0f - s) * od;         // d/du
}

// ---------- table evaluation: ret(c*scale) via asinh + cubic Hermite --------
__device__ __forceinline__ float ret_tab(float c, float scale,
                                         const float2* __restrict__ tab)
{
    const float y  = c * scale;
    const float ay = fabsf(y);
    // u = asinh(y); v = (u + 22)*128 folded into one fma off v_log_f32 (log2)
    const float w  = ay + __builtin_amdgcn_sqrtf(fmaf(ay, ay, 1.0f));
    const float m  = copysignf(VSLOPE, y);
    float v = fmaf(__builtin_amdgcn_logf(w), m, VOFF);
    v = fminf(fmaxf(v, 0.0f), (float)(NTAB - 2) + 0.999f);  // clamp to table
    const int   i   = (int)v;
    const float tau = v - (float)i;

    const float2 A = tab[i];
    const float2 B = tab[i + 1];
    const float t2 = tau * tau;
    const float t3 = t2 * tau;
    // cubic Hermite with segment length HSTEP
    return A.x * (2.0f * t3 - 3.0f * t2 + 1.0f)
         + B.x * (3.0f * t2 - 2.0f * t3)
         + HSTEP * (A.y * (t3 - 2.0f * t2 + tau) + B.y * (t3 - t2));
}

// flux/D0 (D0 folded into the A coefficient)
__device__ __forceinline__ float flux_cell(float ret, float c, float cl, float cr,
                                           int g, int N)
{
    if (g == 0)
        return ret * ((1.0f - c) + (cr - c));
    if (g == N - 1) {
        float rbc = 0.0125f * (cl - c);   // D0*DX*(c[N-2]-c[N-1])
        return ret * ((cl - c) + (rbc - c));
    }
    return ret * (cl + cr - 2.0f * c);
}

__global__ __launch_bounds__(TPB)
void rk4_steps_kernel(const float* __restrict__ src,   // state at step s0 [N]
                      float* __restrict__ out,         // [T, N]
                      const float* __restrict__ wsf,   // table+aux in d_ws
                      int N, int s0, int nsub)
{
    __shared__ float tlds[F4_TOT * 4];   // table + aux (float4-staged)
    __shared__ float la[TPB + 2];        // sentinel slots [0] and [TPB+1]
    __shared__ float lb[TPB + 2];

    const int tid = threadIdx.x;

    // stage table+aux, float4-vectorized
    {
        const float4* __restrict__ s4 = (const float4*)wsf;
        float4* d4 = (float4*)tlds;
        for (int i = tid; i < F4_TOT; i += TPB) d4[i] = s4[i];
    }

    const int g  = blockIdx.x * B_INNER - HALO + tid;  // my global cell (may be OOB)
    const int gi = min(max(g, 0), N - 1);              // clamped load index

    float c = src[gi];

    const bool valid = (tid >= HALO) && (tid < HALO + B_INNER) && (g < N);

    // single launch also writes row 0 (replaces the D2D memcpy)
    if (s0 == 0 && valid) out[g] = c;

    __syncthreads();                  // table staged
    const float2* __restrict__ tab = (const float2*)tlds;
    const float scale = tlds[F_SCALE];

    for (int s = 0; s < nsub; ++s) {
        const float A = tlds[F_A0 + s];   // uniform broadcast, dt*D0

        // stage 1: gather hoisted above write+barrier (latency folds into
        // the barrier's wait)
        float ret1 = ret_tab(c, scale, tab);
        la[tid + 1] = c;
        __syncthreads();
        float cl = la[tid], cr = la[tid + 2];
        float k1 = flux_cell(ret1, c, cl, cr, g, N);
        float c2 = fmaf(0.5f * A, k1, c);

        // stage 2
        float ret2 = ret_tab(c2, scale, tab);
        lb[tid + 1] = c2;
        __syncthreads();
        cl = lb[tid]; cr = lb[tid + 2];
        float k2 = flux_cell(ret2, c2, cl, cr, g, N);
        float c3 = fmaf(0.5f * A, k2, c);

        // stage 3
        float ret3 = ret_tab(c3, scale, tab);
        la[tid + 1] = c3;
        __syncthreads();
        cl = la[tid]; cr = la[tid + 2];
        float k3 = flux_cell(ret3, c3, cl, cr, g, N);
        float c4 = fmaf(A, k3, c);

        // stage 4
        float ret4 = ret_tab(c4, scale, tab);
        lb[tid + 1] = c4;
        __syncthreads();
        cl = lb[tid]; cr = lb[tid + 2];
        float k4 = flux_cell(ret4, c4, cl, cr, g, N);

        c = fmaf(A * (1.0f / 6.0f), k1 + 2.0f * (k2 + k3) + k4, c);

        // write valid inner window of this step's new state
        if (valid)
            out[(size_t)(s0 + s + 1) * N + g] = c;
    }
}

extern "C" void kernel_launch(void* const* d_in, const int* in_sizes, int n_in,
                              void* d_out, int out_size, void* d_ws, size_t ws_size,
                              hipStream_t stream)
{
    const float* c0    = (const float*)d_in[0];
    const float* t     = (const float*)d_in[1];
    const float* W1    = (const float*)d_in[2];
    const float* b1    = (const float*)d_in[3];
    const float* W2    = (const float*)d_in[4];
    const float* b2    = (const float*)d_in[5];
    const float* W3    = (const float*)d_in[6];
    const float* b3    = (const float*)d_in[7];
    const float* W4    = (const float*)d_in[8];
    const float* b4    = (const float*)d_in[9];
    const float* p_exp = (const float*)d_in[10];

    float* out = (float*)d_out;
    float* wsf = (float*)d_ws;   // F_TOT floats = 45196 B

    const int N      = in_sizes[0];       // 65536
    const int nsteps = in_sizes[1] - 1;   // 32

    // build ret table + aux (scale, A[s])
    const int tgrid = (NTAB + 1 + 32 + 255) / 256;
    hipLaunchKernelGGL(build_tab_kernel, dim3(tgrid), dim3(256), 0, stream,
                       W1, b1, W2, b2, W3, b3, W4, b4, p_exp, t, nsteps, wsf);

    const int grid = (N + B_INNER - 1) / B_INNER;  // 256 -> 1 block/CU

    for (int s0 = 0; s0 < nsteps; s0 += S_FUSE) {   // single iteration for T=33
        const int nsub = min(S_FUSE, nsteps - s0);
        const float* src = (s0 == 0) ? c0 : out + (size_t)s0 * N;
        hipLaunchKernelGGL(rk4_steps_kernel, dim3(grid), dim3(TPB), 0, stream,
                           src, out, wsf, N, s0, nsub);
    }
}

// Round 20
// 46.306 us; speedup vs baseline: 1.4106x; 1.0856x over previous
//
#include <hip/hip_runtime.h>
#include <math.h>

// ConcentrationPredictor: 32 RK4 steps of dc/dt = flux(c), per-cell MLP D_eff.
// R20 = R19 (single rk4 dispatch, TPB=512, inner 256, grid 256 = 1 block/CU,
// asinh-space cubic-Hermite table, per-stage barriers, hoisted gathers,
// LDS A[s], sentinel halo buffers, fast-math build_tab) with the table in
// DUPLICATED-PAIR layout: tab4[i] = (v_i, d_i, v_{i+1}, d_{i+1}), so each
// evaluation is ONE ds_read_b128 instead of two ds_read_b64. LDS-pipe issue
// on the gather path halves (the measured dominant term: ~385 cyc/stage/CU
// of DS issue+conflicts vs ~220 VALU). 90KB table + 4KB halos < 160KB at
// 1 block/CU. Same values read, same arithmetic -> bit-identical to R19.

constexpr int TPB     = 512;
constexpr int S_FUSE  = 32;
constexpr int HALO    = 4 * S_FUSE;        // 128
constexpr int B_INNER = TPB - 2 * HALO;    // 256

constexpr int   NTAB   = 5633;             // nodes: u in [-22,22], h = 1/128
constexpr float VSLOPE = 88.72283911167299f;  // ln2 * 128
constexpr float VOFF   = 2816.0f;             // -U_MIN * 128
constexpr float HSTEP  = 0.0078125f;          // h = 1/128
constexpr int   NSEG   = NTAB - 1;            // 5632 float4 segments

// float-layout of d_ws / LDS:
//   [0 .. 4*NSEG)        float4 tab4[i] = (v_i, d_i, v_{i+1}, d_{i+1})
//   [4*NSEG]             scale = 10^p_exp
//   [4*NSEG+1 .. +32]    A[s] = (t[s+1]-t[s]) * 0.3125f
constexpr int F_SCALE = 4 * NSEG;          // 22528
constexpr int F_A0    = 4 * NSEG + 1;      // 22529
constexpr int F_TOT   = 4 * NSEG + 1 + 32; // 22561
constexpr int F4_TOT  = (F_TOT + 3) / 4;   // 5641 float4s staged

__device__ __forceinline__ float fast_tanh(float x) {
    float e = __expf(2.0f * x);
    return 1.0f - 2.0f * __builtin_amdgcn_rcpf(1.0f + e);
}

// ---------- prep: build ret table (value + d/du), duplicated-pair layout ----
__global__ __launch_bounds__(256)
void build_tab_kernel(const float* __restrict__ W1, const float* __restrict__ b1,
                      const float* __restrict__ W2, const float* __restrict__ b2,
                      const float* __restrict__ W3, const float* __restrict__ b3,
                      const float* __restrict__ W4, const float* __restrict__ b4,
                      const float* __restrict__ p_exp, const float* __restrict__ t,
                      int nsteps, float* __restrict__ wsf)
{
    const int i = blockIdx.x * blockDim.x + threadIdx.x;
    if (i > NTAB) {
        const int s = i - NTAB - 1;          // aux: A[s]
        if (s < nsteps && s < 32)
            wsf[F_A0 + s] = (t[s + 1] - t[s]) * 0.3125f;
        return;
    }
    if (i == NTAB) {                          // aux: scale
        wsf[F_SCALE] = powf(10.0f, p_exp[0]);
        return;
    }
    const float u  = -22.0f + (float)i * HSTEP;
    const float y  = sinhf(u);     // MLP input at this node
    const float yd = coshf(u);     // dy/du

    float h[15], hd[15], g[15], gd[15];
#pragma unroll
    for (int j = 0; j < 15; ++j) {
        float a  = fmaf(y, W1[j], b1[j]);
        float ad = yd * W1[j];
        float th = fast_tanh(a);
        h[j]  = th;
        hd[j] = (1.0f - th * th) * ad;
    }
#pragma unroll
    for (int j = 0; j < 15; ++j) {
        float a = b2[j], ad = 0.0f;
#pragma unroll
        for (int k = 0; k < 15; ++k) {
            a  = fmaf(h[k],  W2[k * 15 + j], a);
            ad = fmaf(hd[k], W2[k * 15 + j], ad);
        }
        float th = fast_tanh(a);
        g[j]  = th;
        gd[j] = (1.0f - th * th) * ad;
    }
#pragma unroll
    for (int j = 0; j < 15; ++j) {
        float a = b3[j], ad = 0.0f;
#pragma unroll
        for (int k = 0; k < 15; ++k) {
            a  = fmaf(g[k],  W3[k * 15 + j], a);
            ad = fmaf(gd[k], W3[k * 15 + j], ad);
        }
        float th = fast_tanh(a);
        h[j]  = th;
        hd[j] = (1.0f - th * th) * ad;
    }
    float o = b4[0], od = 0.0f;
#pragma unroll
    for (int k = 0; k < 15; ++k) {
        o  = fmaf(h[k],  W4[k], o);
        od = fmaf(hd[k], W4[k], od);
    }
    const float s = __builtin_amdgcn_rcpf(1.0f + __expf(-o));   // sigmoid
    const float d = s * (1.0f - s) * od;
    // duplicated-pair layout: node i is the left end of segment i and the
    // right end of segment i-1
    if (i < NSEG) {
        wsf[4 * i]     = s;       // tab4[i].x = v_i
        wsf[4 * i + 1] = d;       // tab4[i].y = d_i
    }
    if (i > 0) {
        wsf[4 * (i - 1) + 2] = s; // tab4[i-1].z = v_i
        wsf[4 * (i - 1) + 3] = d; // tab4[i-1].w = d_i
    }
}

// ---------- table evaluation: one ds_read_b128 + cubic Hermite --------------
__device__ __forceinline__ float ret_tab(float c, float scale,
                                         const float4* __restrict__ tab4)
{
    const float y  = c * scale;
    const float ay = fabsf(y);
    // u = asinh(y); v = (u + 22)*128 folded into one fma off v_log_f32 (log2)
    const float w  = ay + __builtin_amdgcn_sqrtf(fmaf(ay, ay, 1.0f));
    const float m  = copysignf(VSLOPE, y);
    float v = fmaf(__builtin_amdgcn_logf(w), m, VOFF);
    v = fminf(fmaxf(v, 0.0f), (float)(NSEG - 1) + 0.999f);  // clamp to table
    const int   i   = (int)v;
    const float tau = v - (float)i;

    const float4 AB = tab4[i];       // (v_i, d_i, v_{i+1}, d_{i+1})
    const float t2 = tau * tau;
    const float t3 = t2 * tau;
    return AB.x * (2.0f * t3 - 3.0f * t2 + 1.0f)
         + AB.z * (3.0f * t2 - 2.0f * t3)
         + HSTEP * (AB.y * (t3 - 2.0f * t2 + tau) + AB.w * (t3 - t2));
}

// flux/D0 (D0 folded into the A coefficient)
__device__ __forceinline__ float flux_cell(float ret, float c, float cl, float cr,
                                           int g, int N)
{
    if (g == 0)
        return ret * ((1.0f - c) + (cr - c));
    if (g == N - 1) {
        float rbc = 0.0125f * (cl - c);   // D0*DX*(c[N-2]-c[N-1])
        return ret * ((cl - c) + (rbc - c));
    }
    return ret * (cl + cr - 2.0f * c);
}

__global__ __launch_bounds__(TPB)
void rk4_steps_kernel(const float* __restrict__ src,   // state at step s0 [N]
                      float* __restrict__ out,         // [T, N]
                      const float* __restrict__ wsf,   // table+aux in d_ws
                      int N, int s0, int nsub)
{
    __shared__ float tlds[F4_TOT * 4];   // table + aux (float4-staged, ~90KB)
    __shared__ float la[TPB + 2];        // sentinel slots [0] and [TPB+1]
    __shared__ float lb[TPB + 2];

    const int tid = threadIdx.x;

    // stage table+aux, float4-vectorized
    {
        const float4* __restrict__ s4 = (const float4*)wsf;
        float4* d4 = (float4*)tlds;
        for (int i = tid; i < F4_TOT; i += TPB) d4[i] = s4[i];
    }

    const int g  = blockIdx.x * B_INNER - HALO + tid;  // my global cell (may be OOB)
    const int gi = min(max(g, 0), N - 1);              // clamped load index

    float c = src[gi];

    const bool valid = (tid >= HALO) && (tid < HALO + B_INNER) && (g < N);

    // single launch also writes row 0 (replaces the D2D memcpy)
    if (s0 == 0 && valid) out[g] = c;

    __syncthreads();                  // table staged
    const float4* __restrict__ tab4 = (const float4*)tlds;
    const float scale = tlds[F_SCALE];

    for (int s = 0; s < nsub; ++s) {
        const float A = tlds[F_A0 + s];   // uniform broadcast, dt*D0

        // stage 1: gather hoisted above write+barrier (latency folds into
        // the barrier's wait)
        float ret1 = ret_tab(c, scale, tab4);
        la[tid + 1] = c;
        __syncthreads();
        float cl = la[tid], cr = la[tid + 2];
        float k1 = flux_cell(ret1, c, cl, cr, g, N);
        float c2 = fmaf(0.5f * A, k1, c);

        // stage 2
        float ret2 = ret_tab(c2, scale, tab4);
        lb[tid + 1] = c2;
        __syncthreads();
        cl = lb[tid]; cr = lb[tid + 2];
        float k2 = flux_cell(ret2, c2, cl, cr, g, N);
        float c3 = fmaf(0.5f * A, k2, c);

        // stage 3
        float ret3 = ret_tab(c3, scale, tab4);
        la[tid + 1] = c3;
        __syncthreads();
        cl = la[tid]; cr = la[tid + 2];
        float k3 = flux_cell(ret3, c3, cl, cr, g, N);
        float c4 = fmaf(A, k3, c);

        // stage 4
        float ret4 = ret_tab(c4, scale, tab4);
        lb[tid + 1] = c4;
        __syncthreads();
        cl = lb[tid]; cr = lb[tid + 2];
        float k4 = flux_cell(ret4, c4, cl, cr, g, N);

        c = fmaf(A * (1.0f / 6.0f), k1 + 2.0f * (k2 + k3) + k4, c);

        // write valid inner window of this step's new state
        if (valid)
            out[(size_t)(s0 + s + 1) * N + g] = c;
    }
}

extern "C" void kernel_launch(void* const* d_in, const int* in_sizes, int n_in,
                              void* d_out, int out_size, void* d_ws, size_t ws_size,
                              hipStream_t stream)
{
    const float* c0    = (const float*)d_in[0];
    const float* t     = (const float*)d_in[1];
    const float* W1    = (const float*)d_in[2];
    const float* b1    = (const float*)d_in[3];
    const float* W2    = (const float*)d_in[4];
    const float* b2    = (const float*)d_in[5];
    const float* W3    = (const float*)d_in[6];
    const float* b3    = (const float*)d_in[7];
    const float* W4    = (const float*)d_in[8];
    const float* b4    = (const float*)d_in[9];
    const float* p_exp = (const float*)d_in[10];

    float* out = (float*)d_out;
    float* wsf = (float*)d_ws;   // F_TOT floats = 90244 B

    const int N      = in_sizes[0];       // 65536
    const int nsteps = in_sizes[1] - 1;   // 32

    // build ret table + aux (scale, A[s])
    const int tgrid = (NTAB + 1 + 32 + 255) / 256;
    hipLaunchKernelGGL(build_tab_kernel, dim3(tgrid), dim3(256), 0, stream,
                       W1, b1, W2, b2, W3, b3, W4, b4, p_exp, t, nsteps, wsf);

    const int grid = (N + B_INNER - 1) / B_INNER;  // 256 -> 1 block/CU

    for (int s0 = 0; s0 < nsteps; s0 += S_FUSE) {   // single iteration for T=33
        const int nsub = min(S_FUSE, nsteps - s0);
        const float* src = (s0 == 0) ? c0 : out + (size_t)s0 * N;
        hipLaunchKernelGGL(rk4_steps_kernel, dim3(grid), dim3(TPB), 0, stream,
                           src, out, wsf, N, s0, nsub);
    }
}